// Round 1
// baseline (33.529 us; speedup 1.0000x reference)
//
#include <hip/hip_runtime.h>

#define N_KPTS 10
#define BS 8
#define HH 180
#define WW 240
#define HW (HH * WW)
#define NPIX (BS * HW)
#define COEFFS_SIZE (BS * (N_KPTS + 1) * HW)

__global__ __launch_bounds__(256) void curve_integrator_kernel(
    const float* __restrict__ deriv,    // [BS][N_KPTS][HW]
    const float* __restrict__ blurry,   // [BS][1][HW]
    const float* __restrict__ kpts,     // [BS][N_KPTS][HW]
    float* __restrict__ out_coeffs,     // [BS][N_KPTS+1][HW]
    float* __restrict__ out_cache)      // [BS][N_KPTS][N_KPTS][HW]
{
    int idx = blockIdx.x * blockDim.x + threadIdx.x;
    if (idx >= NPIX) return;
    int b  = idx / HW;
    int hw = idx - b * HW;

    const float* kp_base = kpts  + (size_t)b * N_KPTS * HW + hw;
    const float* d_base  = deriv + (size_t)b * N_KPTS * HW + hw;

    float kp[N_KPTS], dv[N_KPTS];
#pragma unroll
    for (int i = 0; i < N_KPTS; ++i) {
        kp[i] = kp_base[(size_t)i * HW];
        dv[i] = d_base[(size_t)i * HW];
    }

    float coeffs[N_KPTS];
#pragma unroll
    for (int o = 0; o < N_KPTS; ++o) coeffs[o] = 0.0f;

    float* cache_base = out_cache + (size_t)b * N_KPTS * N_KPTS * HW + hw;

    // reciprocal table 1/(o+1) — compile-time constants after unroll
    const float rcp_tab[N_KPTS] = {
        1.0f, 1.0f/2.0f, 1.0f/3.0f, 1.0f/4.0f, 1.0f/5.0f,
        1.0f/6.0f, 1.0f/7.0f, 1.0f/8.0f, 1.0f/9.0f, 1.0f/10.0f
    };

#pragma unroll
    for (int i = 0; i < N_KPTS; ++i) {
        // c[k] = coeff of x^k in prod_{j != i} (x - kp[j])
        float c[N_KPTS];
        c[0] = 1.0f;
#pragma unroll
        for (int k = 1; k < N_KPTS; ++k) c[k] = 0.0f;

        float denom = 1.0f;
#pragma unroll
        for (int j = 0; j < N_KPTS; ++j) {
            if (j == i) continue;            // elided at compile time (i,j both unrolled)
            float kpj = kp[j];
            denom *= (kp[i] - kpj);
#pragma unroll
            for (int k = N_KPTS - 1; k >= 1; --k)
                c[k] = fmaf(-kpj, c[k], c[k - 1]);
            c[0] = -kpj * c[0];
        }

        float inv = 1.0f / denom;
        float di  = dv[i];
#pragma unroll
        for (int o = 0; o < N_KPTS; ++o) {
            float v = c[o] * (inv * rcp_tab[o]);
            cache_base[((size_t)o * N_KPTS + i) * HW] = v;
            coeffs[o] = fmaf(v, di, coeffs[o]);
        }
    }

    // integral over [-1,1]: only odd o contribute: 2*coeffs[o]/(o+2)
    float integral = 2.0f * coeffs[1] / 3.0f;
    integral += 2.0f * coeffs[3] / 5.0f;
    integral += 2.0f * coeffs[5] / 7.0f;
    integral += 2.0f * coeffs[7] / 9.0f;
    integral += 2.0f * coeffs[9] / 11.0f;

    float baseline = (2.0f * blurry[(size_t)b * HW + hw] - integral) * 0.5f;

    float* oc = out_coeffs + (size_t)b * (N_KPTS + 1) * HW + hw;
    oc[0] = baseline;
#pragma unroll
    for (int o = 0; o < N_KPTS; ++o)
        oc[(size_t)(o + 1) * HW] = coeffs[o];
}

extern "C" void kernel_launch(void* const* d_in, const int* in_sizes, int n_in,
                              void* d_out, int out_size, void* d_ws, size_t ws_size,
                              hipStream_t stream) {
    const float* deriv  = (const float*)d_in[0];
    const float* blurry = (const float*)d_in[1];
    const float* kpts   = (const float*)d_in[2];

    float* out_coeffs = (float*)d_out;                 // BS*(N_KPTS+1)*HW
    float* out_cache  = (float*)d_out + COEFFS_SIZE;   // BS*N_KPTS*N_KPTS*HW

    int threads = 256;
    int blocks  = (NPIX + threads - 1) / threads;      // 1350
    curve_integrator_kernel<<<blocks, threads, 0, stream>>>(
        deriv, blurry, kpts, out_coeffs, out_cache);
}